// Round 4
// baseline (1003.750 us; speedup 1.0000x reference)
//
#include <hip/hip_runtime.h>
#include <math.h>

namespace {
constexpr int Kc = 1024;   // num_embeddings
constexpr int Dd = 64;     // embedding_dim

// numpy pairwise_sum of squares, n=64, exact numpy op order:
//   tmp[d] = fl(a[d]*a[d]) elementwise (rounded BEFORE summing -> contract off)
//   r[j]=tmp[j]; for i=8..56 step 8: r[j]+=tmp[i+j];
//   res = ((r0+r1)+(r2+r3)) + ((r4+r5)+(r6+r7))
__device__ inline float np_sumsq64(const float* __restrict__ a) {
#pragma clang fp contract(off)
    float r[8];
    #pragma unroll
    for (int j = 0; j < 8; ++j) r[j] = a[j] * a[j];
    #pragma unroll
    for (int i = 8; i < 64; i += 8) {
        #pragma unroll
        for (int j = 0; j < 8; ++j) {
            float s = a[i + j] * a[i + j];   // rounded square
            r[j] = r[j] + s;                 // no FMA fusion (contract off)
        }
    }
    return ((r[0] + r[1]) + (r[2] + r[3])) + ((r[4] + r[5]) + (r[6] + r[7]));
}

// ---- pre: ee[k] (bitwise numpy order), hist zero, emb interleave-transpose --
// emb_il[d4][k][4]: element (k,d) at d4*4096 + k*4 + (d&3)  (floats)
// -> k_main lane k reads float4 {d4*4..d4*4+3} at (d4*1024 + k)*16B:
//    consecutive lanes = consecutive 16B -> 1KB fully-coalesced L2 hits.
__global__ void k_ee(const float* __restrict__ emb, float* __restrict__ ee,
                     float* __restrict__ emb_il, unsigned int* __restrict__ hist) {
    const int k = blockIdx.x * blockDim.x + threadIdx.x;
    const float* row = emb + (size_t)k * Dd;
    float xl[64];
    #pragma unroll
    for (int d = 0; d < 64; ++d) xl[d] = row[d];
    ee[k] = np_sumsq64(xl);
    hist[k] = 0u;
    #pragma unroll
    for (int d = 0; d < 64; ++d)
        emb_il[(size_t)(d >> 2) * 4096 + k * 4 + (d & 3)] = xl[d];
}

// ---- main: entry-per-lane, e from L2 (coalesced), x from scalar pipe --------
// Block = 256 thr (4 waves), 64 pixels. Wave w owns entries [256w, 256w+256)
// as 4 tiles of 64 (lane = entry). Inner FMA: v_fmac(acc[p], s_x, v_e):
//  - v_e: global_load_dwordx4 of emb_il -> 1 KB/instr, L2-resident, no LDS.
//  - s_x: inputs[b][d][hw0+p0..p0+15] is 64 contiguous bytes -> s_load_dwordx16
//    (scalar pipe), 1 instr / 64 FMAs.  (v4 lesson: DS broadcast feed = 6x
//    oversubscribed DS pipe; v2/v3 lesson: no 64-elem per-lane arrays.)
// Per-lane state: acc[16]+best[16]+bidx[16] (~80 VGPR, static idx only).
// Numerics identical to v1: per-entry single-acc sequential fmaf d=0..63;
// dist = fmaf(-2, g, xx+ee); argmin exact (dist,idx) lexicographic via
// monotone-packed u64 keys -> partition/order independent, bit-exact unpack.
__global__ __launch_bounds__(256, 4) void k_main(
    const float* __restrict__ inputs, const float* __restrict__ emb,
    const float* __restrict__ emb_il, const float* __restrict__ ee_g,
    float* __restrict__ quant, float* __restrict__ enc,
    float* __restrict__ idx_out, unsigned int* __restrict__ hist,
    float* __restrict__ partials)
{
    __shared__ float s_xx[64];
    __shared__ unsigned long long skey[4][64];

    const int tid = threadIdx.x;
    const int w   = tid >> 6;          // wave id
    const int l   = tid & 63;          // lane = entry-within-tile
    const int blk = blockIdx.x;
    const int b   = blk >> 4;          // 16 blocks per batch image
    const int hw0 = (blk & 15) << 6;   // first pixel (contiguous 64)

    // wave 0: per-pixel ||x||^2 (numpy order), pixel = lane (coalesced loads)
    if (w == 0) {
        const float* xin = inputs + (size_t)b * 65536 + hw0 + l;
        float x[64];
        #pragma unroll
        for (int d = 0; d < 64; ++d) x[d] = xin[d * 1024];
        s_xx[l] = np_sumsq64(x);
    }
    __syncthreads();

    // per-lane ee for this wave's 4 tiles (coalesced)
    float eev[4];
    #pragma unroll
    for (int t = 0; t < 4; ++t) eev[t] = ee_g[(((w << 2) + t) << 6) + l];

    const float* __restrict__ xs = inputs + (size_t)b * 65536 + hw0; // uniform
    const float4* __restrict__ eil = (const float4*)emb_il;
    float4* __restrict__ encb = (float4*)enc + (size_t)blk * 16384;
    unsigned long long mykey = ~0ULL;

    #pragma unroll 1
    for (int g = 0; g < 4; ++g) {          // 4 groups of 16 pixels
        const int p0 = g << 4;
        float best[16]; int bidx[16];
        #pragma unroll
        for (int p = 0; p < 16; ++p) { best[p] = INFINITY; bidx[p] = 0x7fffffff; }

        #pragma unroll 1
        for (int t = 0; t < 4; ++t) {
            const int kme = (((w << 2) + t) << 6) + l;   // this lane's entry
            float acc[16];
            #pragma unroll
            for (int p = 0; p < 16; ++p) acc[p] = 0.f;

            #pragma unroll 4
            for (int d4 = 0; d4 < 16; ++d4) {
                const float4 e4 = eil[d4 * 1024 + kme];        // 1KB coalesced
                const float* __restrict__ xrow = xs + (d4 << 2) * 1024 + p0;
                #pragma unroll
                for (int p = 0; p < 16; ++p) acc[p] = fmaf(xrow[p],        e4.x, acc[p]);
                #pragma unroll
                for (int p = 0; p < 16; ++p) acc[p] = fmaf(xrow[1024 + p], e4.y, acc[p]);
                #pragma unroll
                for (int p = 0; p < 16; ++p) acc[p] = fmaf(xrow[2048 + p], e4.z, acc[p]);
                #pragma unroll
                for (int p = 0; p < 16; ++p) acc[p] = fmaf(xrow[3072 + p], e4.w, acc[p]);
            }

            #pragma unroll
            for (int p = 0; p < 16; ++p) {
                const float A    = s_xx[p0 + p] + eev[t];   // one rounding (v1)
                const float dist = fmaf(-2.f, acc[p], A);   // one rounding (v1)
                const bool lt = (dist < best[p]) || (dist == best[p] && kme < bidx[p]);
                best[p] = lt ? dist : best[p];
                bidx[p] = lt ? kme  : bidx[p];
            }

            // enc zero-fill chunk (g*4+t): 4 float4/thread (256 KB per block)
            {
                float4* z4 = encb + (((g << 2) + t) << 10) + tid;
                const float4 z{0.f, 0.f, 0.f, 0.f};
                z4[0] = z; z4[256] = z; z4[512] = z; z4[768] = z;
            }
        }

        // cross-lane argmin: monotone-packed u64 key, 6-step xor butterfly.
        // mono map is order-preserving f32->u32; key = (mono<<32)|k so
        // unsigned u64 min == (dist asc, k asc) lexicographic, exactly.
        #pragma unroll
        for (int p = 0; p < 16; ++p) {
            unsigned int ub = __float_as_uint(best[p]);
            ub = (ub & 0x80000000u) ? ~ub : (ub | 0x80000000u);
            unsigned long long key =
                ((unsigned long long)ub << 32) | (unsigned int)bidx[p];
            #pragma unroll
            for (int m = 32; m > 0; m >>= 1) {
                const unsigned long long o = __shfl_xor(key, m, 64);
                key = (o < key) ? o : key;
            }
            mykey = (l == p0 + p) ? key : mykey;   // lane l keeps pixel l's key
        }
    }

    skey[w][l] = mykey;
    __syncthreads();   // also drains enc zero-fill stores

    if (tid < 64) {    // coalesced epilogue: pixel = lane
        unsigned long long kk = skey[0][l];
        #pragma unroll
        for (int q = 1; q < 4; ++q) {
            const unsigned long long o = skey[q][l];
            kk = (o < kk) ? o : kk;
        }
        const int bi = (int)(kk & 0xffffffffu);
        unsigned int ub = (unsigned int)(kk >> 32);
        ub = (ub & 0x80000000u) ? (ub & 0x7fffffffu) : ~ub;   // mono inverse
        const float bd = __uint_as_float(ub);                  // bit-exact dist
        const int n = (blk << 6) + l;

        // quantized output: gather codebook row, store NCHW (coalesced per d)
        {
            const float4* ebq = (const float4*)(emb + ((size_t)bi << 6));
            float* qout = quant + (size_t)b * 65536 + hw0 + l;
            #pragma unroll
            for (int i = 0; i < 16; ++i) {
                const float4 v = ebq[i];
                qout[(i * 4 + 0) * 1024] = v.x;
                qout[(i * 4 + 1) * 1024] = v.y;
                qout[(i * 4 + 2) * 1024] = v.z;
                qout[(i * 4 + 3) * 1024] = v.w;
            }
        }

        idx_out[n] = (float)bi;
        atomicAdd(hist + bi, 1u);
        enc[((size_t)n << 10) + bi] = 1.0f;   // one-hot into zeroed row

        // loss partial: dist_min == ||x - e*||^2
        float v = bd;
        #pragma unroll
        for (int off = 32; off > 0; off >>= 1) v += __shfl_down(v, off, 64);
        if (l == 0) partials[blk] = v;
    }
}

// ---- final: perplexity from histogram, loss from partials (1 sync total) ----
__global__ __launch_bounds__(1024) void k_fin(
    const unsigned int* __restrict__ hist, const float* __restrict__ partials,
    float* __restrict__ loss_out, float* __restrict__ perp_out)
{
    __shared__ double sent[16];
    __shared__ double spar[16];
    const int tid = threadIdx.x;

    double pv = (double)hist[tid] * (1.0 / 65536.0);
    double e = pv * log(pv + 1e-10);
    double s = (double)partials[tid];

    #pragma unroll
    for (int off = 32; off > 0; off >>= 1) {
        e += __shfl_down(e, off, 64);
        s += __shfl_down(s, off, 64);
    }
    if ((tid & 63) == 0) { sent[tid >> 6] = e; spar[tid >> 6] = s; }
    __syncthreads();

    if (tid == 0) {
        double ent = 0.0, sum = 0.0;
        #pragma unroll
        for (int w = 0; w < 16; ++w) { ent += sent[w]; sum += spar[w]; }
        double perp = exp(-ent);
        double mean = sum * (1.0 / 4194304.0);   // sum ||x-e||^2 / (N*D)
        double loss = 1.25 * mean + 0.1 * (1024.0 - perp) / 1024.0;
        loss_out[0] = (float)loss;
        perp_out[0] = (float)perp;
    }
}
} // namespace

extern "C" void kernel_launch(void* const* d_in, const int* in_sizes, int n_in,
                              void* d_out, int out_size, void* d_ws, size_t ws_size,
                              hipStream_t stream)
{
    const float* inputs = (const float*)d_in[0];   // [64,64,32,32] fp32
    const float* emb    = (const float*)d_in[1];   // [1024,64] fp32
    float* out = (float*)d_out;

    float* loss_out = out;                            // [1]
    float* quant    = out + 1;                        // [64,64,32,32]
    float* perp_out = out + 1 + 4194304;              // [1]
    float* enc      = out + 2 + 4194304;              // [65536,1024]
    float* idx_out  = out + 2 + 4194304 + 67108864;   // [65536,1]

    unsigned int* hist = (unsigned int*)d_ws;         // [1024] u32
    float* partials    = (float*)d_ws + 1024;         // [1024] f32 (overwritten)
    float* ee          = (float*)d_ws + 2048;         // [1024] f32
    float* emb_il      = (float*)d_ws + 3072;         // [65536] f32 (256 KB)

    k_ee<<<Kc / 256, 256, 0, stream>>>(emb, ee, emb_il, hist);
    k_main<<<65536 / 64, 256, 0, stream>>>(inputs, emb, emb_il, ee, quant, enc,
                                           idx_out, hist, partials);
    k_fin<<<1, 1024, 0, stream>>>(hist, partials, loss_out, perp_out);
}